// Round 19
// baseline (153.102 us; speedup 1.0000x reference)
//
#include <hip/hip_runtime.h>
#include <hip/hip_bf16.h>
#include <hip/hip_fp16.h>
#include <hip/hip_fp8.h>
#include <math.h>

#define NEG_SLOPE 0.2f
#define EPS 1e-16f
#define CHUNK 4096
#define BSH 8                  // bucket shift: 256 nodes per bucket
#define BNODES 256
#define SLAB 10240             // localsort LDS slab capacity (slice ~8704 +- 92)

typedef float floatx2 __attribute__((ext_vector_type(2)));

#if defined(__has_builtin)
# if __has_builtin(__builtin_amdgcn_cvt_pk_f32_fp8)
#  define USE_CVT_BUILTIN 1
# endif
#endif

__device__ __forceinline__ void fp8x4_to_f32(unsigned int u, float& f0, float& f1,
                                             float& f2, float& f3) {
#ifdef USE_CVT_BUILTIN
    floatx2 lo = __builtin_amdgcn_cvt_pk_f32_fp8(u, false);
    floatx2 hi = __builtin_amdgcn_cvt_pk_f32_fp8(u, true);
    f0 = lo.x; f1 = lo.y; f2 = hi.x; f3 = hi.y;
#else
    float4 xv = (float4)(*reinterpret_cast<const __hip_fp8x4_e4m3*>(&u));
    f0 = xv.x; f1 = xv.y; f2 = xv.z; f3 = xv.w;
#endif
}

__device__ __forceinline__ float leaky(float x) {
    return x > 0.f ? x : NEG_SLOPE * x;
}

// ---- block-wide exclusive scan (1024 threads) via wave shfl + 2 barriers ----
__device__ __forceinline__ int block_scan_excl_1024(int v, int t, int* waveS) {
    int lane = t & 63, w = t >> 6;
    int inc = v;
#pragma unroll
    for (int off = 1; off < 64; off <<= 1) {
        int u = __shfl_up(inc, off);
        if (lane >= off) inc += u;
    }
    if (lane == 63) waveS[w] = inc;
    __syncthreads();
    if (w == 0) {
        int s = (lane < 16) ? waveS[lane] : 0;
#pragma unroll
        for (int off = 1; off < 16; off <<= 1) {
            int u = __shfl_up(s, off);
            if (lane >= off) s += u;
        }
        if (lane < 16) waveS[lane] = s;      // inclusive wave sums
    }
    __syncthreads();
    int base = (w > 0) ? waveS[w - 1] : 0;
    return base + inc - v;                   // exclusive
}

// ---------------- K1: per-chunk bucket histogram (LDS atomics only) ----------
__global__ __launch_bounds__(1024) void chunkhist_kernel(
    const int* __restrict__ ei, int E, int ET, int NB, int NC,
    int* __restrict__ cnt) {
    __shared__ int histL[1024];
    int t = threadIdx.x;
    int c = blockIdx.x;
    if (t < NB) histL[t] = 0;
    __syncthreads();
    int e0 = c * CHUNK;
#pragma unroll 4
    for (int i = t; i < CHUNK; i += 1024) {
        int e = e0 + i;
        if (e < ET) {
            int d = (e < E) ? ei[E + e] : (e - E);
            atomicAdd(&histL[d >> BSH], 1);
        }
    }
    __syncthreads();
    if (t < NB) cnt[(size_t)t * NC + c] = histL[t];
}

// ---------------- 2-kernel exclusive scan (wave-shfl based) ----------
__global__ void scan_block(const int* __restrict__ in, int* __restrict__ out,
                           int* __restrict__ partials, int n) {
    __shared__ int waveS[16];
    int t = threadIdx.x;
    int g = blockIdx.x * 1024 + t;
    int v = (g < n) ? in[g] : 0;
    int ex = block_scan_excl_1024(v, t, waveS);
    if (g < n) out[g] = ex;
    if (t == 0) partials[blockIdx.x] = waveS[15];
}

__global__ void scan_partials(int* __restrict__ partials, int P) {
    __shared__ int waveS[16];
    int t = threadIdx.x;
    int v = (t < P) ? partials[t] : 0;
    int ex = block_scan_excl_1024(v, t, waveS);
    if (t < P) partials[t] = ex;
}

// global scan value = scanned[g] + partials[g>>10]
__device__ __forceinline__ int gscan(const int* scanned, const int* partials,
                                     size_t g) {
    return scanned[g] + partials[g >> 10];
}

// ---------------- K4: chunk-local counting sort + coalesced scatter ----------
__global__ __launch_bounds__(1024) void packsort_kernel(
    const int* __restrict__ ei, int E, int ET, int NB, int NC,
    const int* __restrict__ scanned, const int* __restrict__ partials,
    unsigned int* __restrict__ packed) {
    __shared__ unsigned int sortedL[CHUNK];
    __shared__ int gposL[CHUNK];
    __shared__ int histL[1024];
    __shared__ int cursorL[1024];
    __shared__ int diffL[1024];
    __shared__ int waveS[16];
    int t = threadIdx.x;
    int c = blockIdx.x;
    int e0 = c * CHUNK;
    int cw = ET - e0; if (cw > CHUNK) cw = CHUNK;

    if (t < NB) histL[t] = 0;
    __syncthreads();

    unsigned int pk[4]; int bb[4];
#pragma unroll
    for (int k = 0; k < 4; k++) {
        int i = t + k * 1024;
        bb[k] = -1;
        if (i < cw) {
            int e = e0 + i;
            int s, d;
            if (e < E) { s = ei[e]; d = ei[E + e]; } else { s = d = e - E; }
            bb[k] = d >> BSH;
            pk[k] = ((unsigned int)s << BSH) | (unsigned int)(d & (BNODES - 1));
            atomicAdd(&histL[bb[k]], 1);
        }
    }
    __syncthreads();
    int hv = (t < NB) ? histL[t] : 0;
    int ex = block_scan_excl_1024(hv, t, waveS);
    if (t < NB) {
        cursorL[t] = ex;
        size_t g = (size_t)t * NC + c;
        diffL[t] = gscan(scanned, partials, g) - ex;
    }
    __syncthreads();
#pragma unroll
    for (int k = 0; k < 4; k++) {
        if (bb[k] >= 0) {
            int lpos = atomicAdd(&cursorL[bb[k]], 1);
            sortedL[lpos] = pk[k];
            gposL[lpos] = diffL[bb[k]] + lpos;
        }
    }
    __syncthreads();
    for (int i = t; i < cw; i += 1024)
        packed[gposL[i]] = sortedL[i];
}

// ---------------- K5: per-bucket local sort -> flat per-node CSR -------------
__global__ __launch_bounds__(1024) void localsort_kernel(
    const unsigned int* __restrict__ packed, const int* __restrict__ scanned,
    const int* __restrict__ partials, int NB, int NC, int ET,
    int* __restrict__ srt, int* __restrict__ binptr, int N) {
    __shared__ unsigned int slab[SLAB];
    __shared__ int histL[BNODES];
    __shared__ int curL[BNODES];
    __shared__ int waveS[16];
    int t = threadIdx.x;
    int bkt = blockIdx.x;
    int base = bkt * BNODES;
    int ebeg = gscan(scanned, partials, (size_t)bkt * NC);
    int eend = (bkt + 1 < NB) ? gscan(scanned, partials, (size_t)(bkt + 1) * NC) : ET;
    int len = eend - ebeg;
    if (t < BNODES) histL[t] = 0;
    __syncthreads();
    if (len <= SLAB) {
        for (int i = t; i < len; i += 1024) {
            unsigned int p = packed[ebeg + i];
            slab[i] = p;
            atomicAdd(&histL[p & (BNODES - 1)], 1);
        }
        __syncthreads();
        int hv = (t < BNODES) ? histL[t] : 0;
        int ex = block_scan_excl_1024(hv, t, waveS);
        if (t < BNODES) {
            curL[t] = ex;
            int gn = base + t;
            if (gn < N) binptr[gn] = ebeg + ex;
        }
        if (bkt == 0 && t == 0) binptr[N] = ET;
        __syncthreads();
        for (int i = t; i < len; i += 1024) {
            unsigned int p = slab[i];
            int dl = p & (BNODES - 1);
            int pos = ebeg + atomicAdd(&curL[dl], 1);
            srt[pos] = (int)(p >> BSH);
        }
    } else {
        for (int i = ebeg + t; i < eend; i += 1024)
            atomicAdd(&histL[packed[i] & (BNODES - 1)], 1);
        __syncthreads();
        int hv = (t < BNODES) ? histL[t] : 0;
        int ex = block_scan_excl_1024(hv, t, waveS);
        if (t < BNODES) {
            curL[t] = ex;
            int gn = base + t;
            if (gn < N) binptr[gn] = ebeg + ex;
        }
        if (bkt == 0 && t == 0) binptr[N] = ET;
        __syncthreads();
        for (int i = ebeg + t; i < eend; i += 1024) {
            unsigned int p = packed[i];
            int dl = p & (BNODES - 1);
            int pos = ebeg + atomicAdd(&curL[dl], 1);
            srt[pos] = (int)(p >> BSH);
        }
    }
}

// -------- layer 1 GEMM: register-blocked 2 rows x 4 cols per thread ----------
__device__ __forceinline__ void fma4(float4& acc, float sc, const float4& wv) {
    acc.x = fmaf(sc, wv.x, acc.x);
    acc.y = fmaf(sc, wv.y, acc.y);
    acc.z = fmaf(sc, wv.z, acc.z);
    acc.w = fmaf(sc, wv.w, acc.w);
}

__global__ __launch_bounds__(256) void gemm1_kernel(
    const float* __restrict__ x, const float* __restrict__ W1,
    const float4* __restrict__ att_src4, const float4* __restrict__ att_dst4,
    unsigned int* __restrict__ xp1u, float* __restrict__ a_src,
    float* __restrict__ a_dst, int N) {
    __shared__ float4 wS4[128 * 8];
    __shared__ float4 xS4[64 * 32];
    int t = threadIdx.x;
    int base = blockIdx.x * 64;
#pragma unroll
    for (int i = 0; i < 4; i++)
        wS4[t + i * 256] = ((const float4*)W1)[t + i * 256];
#pragma unroll
    for (int i = 0; i < 8; i++) {
        int idx = t + i * 256;                 // [0, 2048)
        int row = idx >> 5, kb = idx & 31;
        xS4[idx] = (base + row < N) ? ((const float4*)x)[(size_t)(base + row) * 32 + kb]
                                    : make_float4(0.f, 0.f, 0.f, 0.f);
    }
    __syncthreads();

    int cq = t & 7;                            // col quad: channels cq*4..cq*4+3
    int rg = t >> 3;                           // row group 0..31 -> rows rg*2, rg*2+1
    const float4* xr0 = xS4 + (rg * 2) * 32;
    const float4* xr1 = xr0 + 32;
    float4 a0 = make_float4(0.f, 0.f, 0.f, 0.f);
    float4 a1 = make_float4(0.f, 0.f, 0.f, 0.f);
#pragma unroll 4
    for (int kb = 0; kb < 32; kb++) {
        float4 x0 = xr0[kb];
        float4 x1 = xr1[kb];
        float4 w0 = wS4[(kb * 4 + 0) * 8 + cq];
        float4 w1 = wS4[(kb * 4 + 1) * 8 + cq];
        float4 w2 = wS4[(kb * 4 + 2) * 8 + cq];
        float4 w3 = wS4[(kb * 4 + 3) * 8 + cq];
        fma4(a0, x0.x, w0); fma4(a0, x0.y, w1); fma4(a0, x0.z, w2); fma4(a0, x0.w, w3);
        fma4(a1, x1.x, w0); fma4(a1, x1.y, w1); fma4(a1, x1.z, w2); fma4(a1, x1.w, w3);
    }

    float4 asv = att_src4[cq];
    float4 adv = att_dst4[cq];
    int r0 = base + rg * 2, r1 = r0 + 1;
    float va0 = a0.x * asv.x + a0.y * asv.y + a0.z * asv.z + a0.w * asv.w;
    float vd0 = a0.x * adv.x + a0.y * adv.y + a0.z * adv.z + a0.w * adv.w;
    float va1 = a1.x * asv.x + a1.y * asv.y + a1.z * asv.z + a1.w * asv.w;
    float vd1 = a1.x * adv.x + a1.y * adv.y + a1.z * adv.z + a1.w * adv.w;
#pragma unroll
    for (int off = 1; off <= 2; off <<= 1) {
        va0 += __shfl_xor(va0, off);
        vd0 += __shfl_xor(vd0, off);
        va1 += __shfl_xor(va1, off);
        vd1 += __shfl_xor(vd1, off);
    }
    if (r0 < N) {
        __hip_fp8x4_e4m3 q0(a0);
        xp1u[(size_t)r0 * 8 + cq] = *(unsigned int*)&q0;
        if ((cq & 3) == 0) {
            int h = cq >> 2;
            a_src[r0 * 2 + h] = va0;
            a_dst[r0 * 2 + h] = vd0;
        }
    }
    if (r1 < N) {
        __hip_fp8x4_e4m3 q1(a1);
        xp1u[(size_t)r1 * 8 + cq] = *(unsigned int*)&q1;
        if ((cq & 3) == 0) {
            int h = cq >> 2;
            a_src[r1 * 2 + h] = va1;
            a_dst[r1 * 2 + h] = vd1;
        }
    }
}

// ---- fused layer-1 aggregation + normalize + relu + @W2 ----------------------
// 2 nodes per 64-lane wave: both staging chains (srt load -> a_src gather ->
// exp -> pack, ~500cy latency each) issue back-to-back and overlap; tiered
// static-unroll consume per node; interleaved shuffle reduces.
#define AGG1_CONSUME(KN, SL, PKL, MA0, MA1, MA2, MA3, MSS)                      \
    _Pragma("unroll")                                                           \
    for (int k = 0; k < KN; k++) {                                              \
        int es = k * 8 + eg;                                                    \
        int sk = __shfl(SL, es);                                                \
        unsigned int pw = (unsigned int)__shfl((int)PKL, es);                   \
        float ek = __uint_as_float(hsel ? (pw & 0xFFFF0000u) : (pw << 16));     \
        unsigned int u = *(const unsigned int*)(xpb + (size_t)sk * 32);         \
        float f0, f1, f2, f3;                                                   \
        fp8x4_to_f32(u, f0, f1, f2, f3);                                        \
        MA0 = fmaf(ek, f0, MA0);                                                \
        MA1 = fmaf(ek, f1, MA1);                                                \
        MA2 = fmaf(ek, f2, MA2);                                                \
        MA3 = fmaf(ek, f3, MA3);                                                \
        MSS += ek;                                                              \
    }

#define AGG1_TIERS(CW, SL, PKL, MA0, MA1, MA2, MA3, MSS)                        \
    if (CW > 48)      { AGG1_CONSUME(8, SL, PKL, MA0, MA1, MA2, MA3, MSS) }     \
    else if (CW > 32) { AGG1_CONSUME(6, SL, PKL, MA0, MA1, MA2, MA3, MSS) }     \
    else if (CW > 16) { AGG1_CONSUME(4, SL, PKL, MA0, MA1, MA2, MA3, MSS) }     \
    else if (CW > 0)  { AGG1_CONSUME(2, SL, PKL, MA0, MA1, MA2, MA3, MSS) }

__global__ __launch_bounds__(256) void agg1_kernel(
    const int* __restrict__ binptr, const int* __restrict__ srt,
    const float2* __restrict__ a_src2, const float2* __restrict__ a_dst2,
    const unsigned char* __restrict__ xp1f8, const float* __restrict__ b1,
    const float* __restrict__ W2, float* __restrict__ xp2, int N) {
    int tg = blockIdx.x * blockDim.x + threadIdx.x;
    int wv = tg >> 6;
    int n0 = wv * 2;
    if (n0 >= N) return;
    int n1 = n0 + 1;
    bool has1 = n1 < N;
    int lane = threadIdx.x & 63;
    int eg = lane >> 3;            // edge slot 0..7
    int cq = lane & 7;             // channel quad: channels cq*4..cq*4+3
    int hsel = cq >> 2;            // head for this lane's channels
    int beg0 = binptr[n0], end0 = binptr[n0 + 1];
    int beg1 = has1 ? binptr[n1] : 0;
    int end1 = has1 ? binptr[n1 + 1] : 0;
    float2 ad0 = a_dst2[n0];
    float2 ad1 = has1 ? a_dst2[n1] : ad0;
    const unsigned char* xpb = xp1f8 + cq * 4;

    float a00 = 0.f, a01 = 0.f, a02 = 0.f, a03 = 0.f, ss0 = 0.f;
    float a10 = 0.f, a11 = 0.f, a12 = 0.f, a13 = 0.f, ss1 = 0.f;
    int i0 = beg0, i1 = beg1;
    while (i0 < end0 || i1 < end1) {
        int cw0 = end0 - i0; cw0 = cw0 < 0 ? 0 : (cw0 > 64 ? 64 : cw0);
        int cw1 = end1 - i1; cw1 = cw1 < 0 ? 0 : (cw1 > 64 ? 64 : cw1);
        int sA = 0, sB = 0;
        unsigned int pkA = 0u, pkB = 0u;
        if (lane < cw0) {
            sA = srt[i0 + lane];
            float2 as = a_src2[sA];
            float e0 = __expf(leaky(as.x + ad0.x));
            float e1 = __expf(leaky(as.y + ad0.y));
            pkA = ((__float_as_uint(e1) + 0x8000u) & 0xFFFF0000u) |
                  ((__float_as_uint(e0) + 0x8000u) >> 16);
        }
        if (lane < cw1) {
            sB = srt[i1 + lane];
            float2 as = a_src2[sB];
            float e0 = __expf(leaky(as.x + ad1.x));
            float e1 = __expf(leaky(as.y + ad1.y));
            pkB = ((__float_as_uint(e1) + 0x8000u) & 0xFFFF0000u) |
                  ((__float_as_uint(e0) + 0x8000u) >> 16);
        }
        AGG1_TIERS(cw0, sA, pkA, a00, a01, a02, a03, ss0)
        AGG1_TIERS(cw1, sB, pkB, a10, a11, a12, a13, ss1)
        i0 += 64;
        i1 += 64;
    }
    // interleaved reduce across the 8 edge slots (lane bits 3..5)
#pragma unroll
    for (int off = 8; off <= 32; off <<= 1) {
        a00 += __shfl_xor(a00, off);
        a10 += __shfl_xor(a10, off);
        a01 += __shfl_xor(a01, off);
        a11 += __shfl_xor(a11, off);
        a02 += __shfl_xor(a02, off);
        a12 += __shfl_xor(a12, off);
        a03 += __shfl_xor(a03, off);
        a13 += __shfl_xor(a13, off);
        ss0 += __shfl_xor(ss0, off);
        ss1 += __shfl_xor(ss1, off);
    }
    float inv0 = 1.f / (ss0 + EPS);
    float inv1 = 1.f / (ss1 + EPS);
    int j0 = cq * 4;
    float bb0 = b1[j0 + 0], bb1 = b1[j0 + 1], bb2 = b1[j0 + 2], bb3 = b1[j0 + 3];
    float ww0 = W2[j0 + 0], ww1 = W2[j0 + 1], ww2 = W2[j0 + 2], ww3 = W2[j0 + 3];
    float p0, p1;
    {
        float h0 = fmaxf(a00 * inv0 + bb0, 0.f);
        float h1 = fmaxf(a01 * inv0 + bb1, 0.f);
        float h2 = fmaxf(a02 * inv0 + bb2, 0.f);
        float h3 = fmaxf(a03 * inv0 + bb3, 0.f);
        p0 = h0 * ww0;
        p0 = fmaf(h1, ww1, p0);
        p0 = fmaf(h2, ww2, p0);
        p0 = fmaf(h3, ww3, p0);
    }
    {
        float h0 = fmaxf(a10 * inv1 + bb0, 0.f);
        float h1 = fmaxf(a11 * inv1 + bb1, 0.f);
        float h2 = fmaxf(a12 * inv1 + bb2, 0.f);
        float h3 = fmaxf(a13 * inv1 + bb3, 0.f);
        p1 = h0 * ww0;
        p1 = fmaf(h1, ww1, p1);
        p1 = fmaf(h2, ww2, p1);
        p1 = fmaf(h3, ww3, p1);
    }
    // interleaved reduce across the 8 channel quads (lane bits 0..2)
#pragma unroll
    for (int off = 1; off <= 4; off <<= 1) {
        p0 += __shfl_xor(p0, off);
        p1 += __shfl_xor(p1, off);
    }
    if (lane == 0) {
        xp2[n0] = p0;
        if (has1) xp2[n1] = p1;
    }
}

// ---- fused layer-2 aggregation: 2 nodes per 32-lane slot (2x gather MLP) ----
__global__ __launch_bounds__(256) void agg2_kernel(
    const int* __restrict__ binptr, const int* __restrict__ srt,
    const float* __restrict__ xp2, const float* __restrict__ as2p,
    const float* __restrict__ ad2p, const float* __restrict__ b2,
    float* __restrict__ partial, int N) {
    int slot = (blockIdx.x * blockDim.x + threadIdx.x) >> 5;
    int j = threadIdx.x & 31;
    int nslots = (gridDim.x * blockDim.x) >> 5;
    float as2 = as2p[0], ad2 = ad2p[0], bb = b2[0];
    float val = 0.f;
    for (int n0 = slot; n0 < N; n0 += 2 * nslots) {
        int n1 = n0 + nslots;
        bool has1 = n1 < N;
        int beg0 = binptr[n0], end0 = binptr[n0 + 1];
        int beg1 = has1 ? binptr[n1] : 0;
        int end1 = has1 ? binptr[n1 + 1] : 0;
        float xd0 = xp2[n0] * ad2;
        float xd1 = has1 ? xp2[n1] * ad2 : 0.f;
        float se0 = 0.f, sa0 = 0.f, se1 = 0.f, sa1 = 0.f;
        int it0 = (end0 - beg0 - j + 31) >> 5;   // iterations for lane j
        int it1 = (end1 - beg1 - j + 31) >> 5;
        int itm = it0 > it1 ? it0 : it1;
        for (int k = 0; k < itm; k++) {
            int i0 = beg0 + j + k * 32;
            int i1 = beg1 + j + k * 32;
            if (i0 < end0) {
                float xs = xp2[srt[i0]];
                float ex = __expf(leaky(fmaf(xs, as2, xd0)));
                se0 += ex; sa0 = fmaf(ex, xs, sa0);
            }
            if (has1 && i1 < end1) {
                float xs = xp2[srt[i1]];
                float ex = __expf(leaky(fmaf(xs, as2, xd1)));
                se1 += ex; sa1 = fmaf(ex, xs, sa1);
            }
        }
#pragma unroll
        for (int off = 16; off >= 1; off >>= 1) {
            se0 += __shfl_xor(se0, off);
            sa0 += __shfl_xor(sa0, off);
            se1 += __shfl_xor(se1, off);
            sa1 += __shfl_xor(sa1, off);
        }
        if (j == 0) {
            val += sa0 / (se0 + EPS) + bb;
            if (has1) val += sa1 / (se1 + EPS) + bb;
        }
    }
#pragma unroll
    for (int off = 32; off >= 1; off >>= 1) val += __shfl_xor(val, off);
    __shared__ float ls[4];
    int lane = threadIdx.x & 63, w = threadIdx.x >> 6;
    if (lane == 0) ls[w] = val;
    __syncthreads();
    if (threadIdx.x == 0) partial[blockIdx.x] = ls[0] + ls[1] + ls[2] + ls[3];
}

// ---------------- final: out[0] = sum of partials ----------------
__global__ void final_reduce(const float* __restrict__ partial, float* __restrict__ out,
                             int P) {
    int t = threadIdx.x;
    float v = 0.f;
    for (int i = t; i < P; i += 1024) v += partial[i];
#pragma unroll
    for (int off = 32; off >= 1; off >>= 1) v += __shfl_xor(v, off);
    __shared__ float ls[16];
    int w = t >> 6, lane = t & 63;
    if (lane == 0) ls[w] = v;
    __syncthreads();
    if (t == 0) {
        float s = 0.f;
        for (int i = 0; i < 16; i++) s += ls[i];
        out[0] = s;
    }
}

extern "C" void kernel_launch(void* const* d_in, const int* in_sizes, int n_in,
                              void* d_out, int out_size, void* d_ws, size_t ws_size,
                              hipStream_t stream) {
    const float* x        = (const float*)d_in[0];
    const int*   ei       = (const int*)d_in[1];
    const float* W1       = (const float*)d_in[2];
    const float* att_src1 = (const float*)d_in[3];
    const float* att_dst1 = (const float*)d_in[4];
    const float* b1       = (const float*)d_in[5];
    const float* W2       = (const float*)d_in[6];
    const float* att_src2 = (const float*)d_in[7];
    const float* att_dst2 = (const float*)d_in[8];
    const float* b2       = (const float*)d_in[9];
    float* out = (float*)d_out;

    int N = in_sizes[0] / 128;
    int E = in_sizes[1] / 2;
    int ET = E + N;
    int NB = (N + BNODES - 1) / BNODES;        // 391 buckets
    int NC = (ET + CHUNK - 1) / CHUNK;         // 806 chunks
    int n_scan = NB * NC;                      // ~315K
    int nb2 = (n_scan + 1023) / 1024;          // ~308 scan blocks (<=1024)
    const int AGG2_BLOCKS = 2048;

    char* w = (char*)d_ws;
    unsigned char* xp1f8 = (unsigned char*)w; w += (size_t)N * 32;
    float* a_src   = (float*)w;  w += sizeof(float) * (size_t)N * 2;
    float* a_dst   = (float*)w;  w += sizeof(float) * (size_t)N * 2;
    float* xp2     = (float*)w;  w += sizeof(float) * (size_t)N;
    int* cnt       = (int*)w;    w += sizeof(int) * (size_t)n_scan;
    int* scanned   = (int*)w;    w += sizeof(int) * (size_t)(n_scan + 4);
    int* partials  = (int*)w;    w += sizeof(int) * 1024;
    float* part2   = (float*)w;  w += sizeof(float) * (size_t)AGG2_BLOCKS;
    unsigned int* packed = (unsigned int*)w; w += sizeof(unsigned int) * (size_t)ET;
    int* srt       = (int*)w;    w += sizeof(int) * (size_t)ET;
    int* binptr    = (int*)w;    w += sizeof(int) * (size_t)(N + 1);

    gemm1_kernel<<<(N + 63) / 64, 256, 0, stream>>>(x, W1,
                                                    (const float4*)att_src1,
                                                    (const float4*)att_dst1,
                                                    (unsigned int*)xp1f8, a_src,
                                                    a_dst, N);
    chunkhist_kernel<<<NC, 1024, 0, stream>>>(ei, E, ET, NB, NC, cnt);
    scan_block<<<nb2, 1024, 0, stream>>>(cnt, scanned, partials, n_scan);
    scan_partials<<<1, 1024, 0, stream>>>(partials, nb2);
    packsort_kernel<<<NC, 1024, 0, stream>>>(ei, E, ET, NB, NC, scanned, partials,
                                             packed);
    localsort_kernel<<<NB, 1024, 0, stream>>>(packed, scanned, partials, NB, NC, ET,
                                              srt, binptr, N);
    int agg1_waves = (N + 1) / 2;
    agg1_kernel<<<(agg1_waves * 64 + 255) / 256, 256, 0, stream>>>(binptr, srt,
                                                          (const float2*)a_src,
                                                          (const float2*)a_dst,
                                                          xp1f8, b1, W2, xp2, N);
    agg2_kernel<<<AGG2_BLOCKS, 256, 0, stream>>>(binptr, srt, xp2,
                                                 att_src2, att_dst2, b2, part2, N);
    final_reduce<<<1, 1024, 0, stream>>>(part2, out, AGG2_BLOCKS);
}

// Round 20
// 150.142 us; speedup vs baseline: 1.0197x; 1.0197x over previous
//
#include <hip/hip_runtime.h>
#include <hip/hip_bf16.h>
#include <hip/hip_fp16.h>
#include <hip/hip_fp8.h>
#include <math.h>

#define NEG_SLOPE 0.2f
#define EPS 1e-16f
#define CHUNK 4096
#define BSH 8                  // bucket shift: 256 nodes per bucket
#define BNODES 256
#define SLAB 10240             // localsort LDS slab capacity (slice ~8704 +- 92)

typedef float floatx2 __attribute__((ext_vector_type(2)));

#if defined(__has_builtin)
# if __has_builtin(__builtin_amdgcn_cvt_pk_f32_fp8)
#  define USE_CVT_BUILTIN 1
# endif
#endif

__device__ __forceinline__ void fp8x4_to_f32(unsigned int u, float& f0, float& f1,
                                             float& f2, float& f3) {
#ifdef USE_CVT_BUILTIN
    floatx2 lo = __builtin_amdgcn_cvt_pk_f32_fp8(u, false);
    floatx2 hi = __builtin_amdgcn_cvt_pk_f32_fp8(u, true);
    f0 = lo.x; f1 = lo.y; f2 = hi.x; f3 = hi.y;
#else
    float4 xv = (float4)(*reinterpret_cast<const __hip_fp8x4_e4m3*>(&u));
    f0 = xv.x; f1 = xv.y; f2 = xv.z; f3 = xv.w;
#endif
}

__device__ __forceinline__ float leaky(float x) {
    return x > 0.f ? x : NEG_SLOPE * x;
}

// ---- block-wide exclusive scan (1024 threads) via wave shfl + 2 barriers ----
__device__ __forceinline__ int block_scan_excl_1024(int v, int t, int* waveS) {
    int lane = t & 63, w = t >> 6;
    int inc = v;
#pragma unroll
    for (int off = 1; off < 64; off <<= 1) {
        int u = __shfl_up(inc, off);
        if (lane >= off) inc += u;
    }
    if (lane == 63) waveS[w] = inc;
    __syncthreads();
    if (w == 0) {
        int s = (lane < 16) ? waveS[lane] : 0;
#pragma unroll
        for (int off = 1; off < 16; off <<= 1) {
            int u = __shfl_up(s, off);
            if (lane >= off) s += u;
        }
        if (lane < 16) waveS[lane] = s;      // inclusive wave sums
    }
    __syncthreads();
    int base = (w > 0) ? waveS[w - 1] : 0;
    return base + inc - v;                   // exclusive
}

// ---------------- K1: per-chunk bucket histogram (LDS atomics only) ----------
__global__ __launch_bounds__(1024) void chunkhist_kernel(
    const int* __restrict__ ei, int E, int ET, int NB, int NC,
    int* __restrict__ cnt) {
    __shared__ int histL[1024];
    int t = threadIdx.x;
    int c = blockIdx.x;
    if (t < NB) histL[t] = 0;
    __syncthreads();
    int e0 = c * CHUNK;
#pragma unroll 4
    for (int i = t; i < CHUNK; i += 1024) {
        int e = e0 + i;
        if (e < ET) {
            int d = (e < E) ? ei[E + e] : (e - E);
            atomicAdd(&histL[d >> BSH], 1);
        }
    }
    __syncthreads();
    if (t < NB) cnt[(size_t)t * NC + c] = histL[t];
}

// ---------------- 2-kernel exclusive scan (wave-shfl based) ----------
__global__ void scan_block(const int* __restrict__ in, int* __restrict__ out,
                           int* __restrict__ partials, int n) {
    __shared__ int waveS[16];
    int t = threadIdx.x;
    int g = blockIdx.x * 1024 + t;
    int v = (g < n) ? in[g] : 0;
    int ex = block_scan_excl_1024(v, t, waveS);
    if (g < n) out[g] = ex;
    if (t == 0) partials[blockIdx.x] = waveS[15];
}

__global__ void scan_partials(int* __restrict__ partials, int P) {
    __shared__ int waveS[16];
    int t = threadIdx.x;
    int v = (t < P) ? partials[t] : 0;
    int ex = block_scan_excl_1024(v, t, waveS);
    if (t < P) partials[t] = ex;
}

// global scan value = scanned[g] + partials[g>>10]
__device__ __forceinline__ int gscan(const int* scanned, const int* partials,
                                     size_t g) {
    return scanned[g] + partials[g >> 10];
}

// ---------------- K4: chunk-local counting sort + coalesced scatter ----------
__global__ __launch_bounds__(1024) void packsort_kernel(
    const int* __restrict__ ei, int E, int ET, int NB, int NC,
    const int* __restrict__ scanned, const int* __restrict__ partials,
    unsigned int* __restrict__ packed) {
    __shared__ unsigned int sortedL[CHUNK];
    __shared__ int gposL[CHUNK];
    __shared__ int histL[1024];
    __shared__ int cursorL[1024];
    __shared__ int diffL[1024];
    __shared__ int waveS[16];
    int t = threadIdx.x;
    int c = blockIdx.x;
    int e0 = c * CHUNK;
    int cw = ET - e0; if (cw > CHUNK) cw = CHUNK;

    if (t < NB) histL[t] = 0;
    __syncthreads();

    unsigned int pk[4]; int bb[4];
#pragma unroll
    for (int k = 0; k < 4; k++) {
        int i = t + k * 1024;
        bb[k] = -1;
        if (i < cw) {
            int e = e0 + i;
            int s, d;
            if (e < E) { s = ei[e]; d = ei[E + e]; } else { s = d = e - E; }
            bb[k] = d >> BSH;
            pk[k] = ((unsigned int)s << BSH) | (unsigned int)(d & (BNODES - 1));
            atomicAdd(&histL[bb[k]], 1);
        }
    }
    __syncthreads();
    int hv = (t < NB) ? histL[t] : 0;
    int ex = block_scan_excl_1024(hv, t, waveS);
    if (t < NB) {
        cursorL[t] = ex;
        size_t g = (size_t)t * NC + c;
        diffL[t] = gscan(scanned, partials, g) - ex;
    }
    __syncthreads();
#pragma unroll
    for (int k = 0; k < 4; k++) {
        if (bb[k] >= 0) {
            int lpos = atomicAdd(&cursorL[bb[k]], 1);
            sortedL[lpos] = pk[k];
            gposL[lpos] = diffL[bb[k]] + lpos;
        }
    }
    __syncthreads();
    for (int i = t; i < cw; i += 1024)
        packed[gposL[i]] = sortedL[i];
}

// ---------------- K5: per-bucket local sort -> flat per-node CSR -------------
__global__ __launch_bounds__(1024) void localsort_kernel(
    const unsigned int* __restrict__ packed, const int* __restrict__ scanned,
    const int* __restrict__ partials, int NB, int NC, int ET,
    int* __restrict__ srt, int* __restrict__ binptr, int N) {
    __shared__ unsigned int slab[SLAB];
    __shared__ int histL[BNODES];
    __shared__ int curL[BNODES];
    __shared__ int waveS[16];
    int t = threadIdx.x;
    int bkt = blockIdx.x;
    int base = bkt * BNODES;
    int ebeg = gscan(scanned, partials, (size_t)bkt * NC);
    int eend = (bkt + 1 < NB) ? gscan(scanned, partials, (size_t)(bkt + 1) * NC) : ET;
    int len = eend - ebeg;
    if (t < BNODES) histL[t] = 0;
    __syncthreads();
    if (len <= SLAB) {
        for (int i = t; i < len; i += 1024) {
            unsigned int p = packed[ebeg + i];
            slab[i] = p;
            atomicAdd(&histL[p & (BNODES - 1)], 1);
        }
        __syncthreads();
        int hv = (t < BNODES) ? histL[t] : 0;
        int ex = block_scan_excl_1024(hv, t, waveS);
        if (t < BNODES) {
            curL[t] = ex;
            int gn = base + t;
            if (gn < N) binptr[gn] = ebeg + ex;
        }
        if (bkt == 0 && t == 0) binptr[N] = ET;
        __syncthreads();
        for (int i = t; i < len; i += 1024) {
            unsigned int p = slab[i];
            int dl = p & (BNODES - 1);
            int pos = ebeg + atomicAdd(&curL[dl], 1);
            srt[pos] = (int)(p >> BSH);
        }
    } else {
        for (int i = ebeg + t; i < eend; i += 1024)
            atomicAdd(&histL[packed[i] & (BNODES - 1)], 1);
        __syncthreads();
        int hv = (t < BNODES) ? histL[t] : 0;
        int ex = block_scan_excl_1024(hv, t, waveS);
        if (t < BNODES) {
            curL[t] = ex;
            int gn = base + t;
            if (gn < N) binptr[gn] = ebeg + ex;
        }
        if (bkt == 0 && t == 0) binptr[N] = ET;
        __syncthreads();
        for (int i = ebeg + t; i < eend; i += 1024) {
            unsigned int p = packed[i];
            int dl = p & (BNODES - 1);
            int pos = ebeg + atomicAdd(&curL[dl], 1);
            srt[pos] = (int)(p >> BSH);
        }
    }
}

// -------- layer 1 GEMM: register-blocked 2 rows x 4 cols per thread ----------
__device__ __forceinline__ void fma4(float4& acc, float sc, const float4& wv) {
    acc.x = fmaf(sc, wv.x, acc.x);
    acc.y = fmaf(sc, wv.y, acc.y);
    acc.z = fmaf(sc, wv.z, acc.z);
    acc.w = fmaf(sc, wv.w, acc.w);
}

__global__ __launch_bounds__(256) void gemm1_kernel(
    const float* __restrict__ x, const float* __restrict__ W1,
    const float4* __restrict__ att_src4, const float4* __restrict__ att_dst4,
    unsigned int* __restrict__ xp1u, float* __restrict__ a_src,
    float* __restrict__ a_dst, int N) {
    __shared__ float4 wS4[128 * 8];
    __shared__ float4 xS4[64 * 32];
    int t = threadIdx.x;
    int base = blockIdx.x * 64;
#pragma unroll
    for (int i = 0; i < 4; i++)
        wS4[t + i * 256] = ((const float4*)W1)[t + i * 256];
#pragma unroll
    for (int i = 0; i < 8; i++) {
        int idx = t + i * 256;                 // [0, 2048)
        int row = idx >> 5, kb = idx & 31;
        xS4[idx] = (base + row < N) ? ((const float4*)x)[(size_t)(base + row) * 32 + kb]
                                    : make_float4(0.f, 0.f, 0.f, 0.f);
    }
    __syncthreads();

    int cq = t & 7;                            // col quad: channels cq*4..cq*4+3
    int rg = t >> 3;                           // row group 0..31 -> rows rg*2, rg*2+1
    const float4* xr0 = xS4 + (rg * 2) * 32;
    const float4* xr1 = xr0 + 32;
    float4 a0 = make_float4(0.f, 0.f, 0.f, 0.f);
    float4 a1 = make_float4(0.f, 0.f, 0.f, 0.f);
#pragma unroll 4
    for (int kb = 0; kb < 32; kb++) {
        float4 x0 = xr0[kb];
        float4 x1 = xr1[kb];
        float4 w0 = wS4[(kb * 4 + 0) * 8 + cq];
        float4 w1 = wS4[(kb * 4 + 1) * 8 + cq];
        float4 w2 = wS4[(kb * 4 + 2) * 8 + cq];
        float4 w3 = wS4[(kb * 4 + 3) * 8 + cq];
        fma4(a0, x0.x, w0); fma4(a0, x0.y, w1); fma4(a0, x0.z, w2); fma4(a0, x0.w, w3);
        fma4(a1, x1.x, w0); fma4(a1, x1.y, w1); fma4(a1, x1.z, w2); fma4(a1, x1.w, w3);
    }

    float4 asv = att_src4[cq];
    float4 adv = att_dst4[cq];
    int r0 = base + rg * 2, r1 = r0 + 1;
    float va0 = a0.x * asv.x + a0.y * asv.y + a0.z * asv.z + a0.w * asv.w;
    float vd0 = a0.x * adv.x + a0.y * adv.y + a0.z * adv.z + a0.w * adv.w;
    float va1 = a1.x * asv.x + a1.y * asv.y + a1.z * asv.z + a1.w * asv.w;
    float vd1 = a1.x * adv.x + a1.y * adv.y + a1.z * adv.z + a1.w * adv.w;
#pragma unroll
    for (int off = 1; off <= 2; off <<= 1) {
        va0 += __shfl_xor(va0, off);
        vd0 += __shfl_xor(vd0, off);
        va1 += __shfl_xor(va1, off);
        vd1 += __shfl_xor(vd1, off);
    }
    if (r0 < N) {
        __hip_fp8x4_e4m3 q0(a0);
        xp1u[(size_t)r0 * 8 + cq] = *(unsigned int*)&q0;
        if ((cq & 3) == 0) {
            int h = cq >> 2;
            a_src[r0 * 2 + h] = va0;
            a_dst[r0 * 2 + h] = vd0;
        }
    }
    if (r1 < N) {
        __hip_fp8x4_e4m3 q1(a1);
        xp1u[(size_t)r1 * 8 + cq] = *(unsigned int*)&q1;
        if ((cq & 3) == 0) {
            int h = cq >> 2;
            a_src[r1 * 2 + h] = va1;
            a_dst[r1 * 2 + h] = vd1;
        }
    }
}

// ---- fused layer-1 aggregation + normalize + relu + @W2 ----------------------
// Round-17 proven best (48.4-48.7 us): 1 node/wave, shuffle staging, tiered
// static unroll {2,4,6,8}, bf16-packed weights, HW cvt_pk fp8 unpack.
#define AGG1_CONSUME(KN)                                                        \
    _Pragma("unroll")                                                           \
    for (int k = 0; k < KN; k++) {                                              \
        int es = k * 8 + eg;                                                    \
        int sk = __shfl(s_l, es);                                               \
        unsigned int pw = (unsigned int)__shfl((int)pk_l, es);                  \
        float ek = __uint_as_float(hsel ? (pw & 0xFFFF0000u) : (pw << 16));     \
        unsigned int u = *(const unsigned int*)(xpb + (size_t)sk * 32);         \
        float f0, f1, f2, f3;                                                   \
        fp8x4_to_f32(u, f0, f1, f2, f3);                                        \
        acc0 = fmaf(ek, f0, acc0);                                              \
        acc1 = fmaf(ek, f1, acc1);                                              \
        acc2 = fmaf(ek, f2, acc2);                                              \
        acc3 = fmaf(ek, f3, acc3);                                              \
        ssum += ek;                                                             \
    }

__global__ __launch_bounds__(256) void agg1_kernel(
    const int* __restrict__ binptr, const int* __restrict__ srt,
    const float2* __restrict__ a_src2, const float2* __restrict__ a_dst2,
    const unsigned char* __restrict__ xp1f8, const float* __restrict__ b1,
    const float* __restrict__ W2, float* __restrict__ xp2, int N) {
    int tg = blockIdx.x * blockDim.x + threadIdx.x;
    int n = tg >> 6;
    int lane = threadIdx.x & 63;
    if (n >= N) return;
    int eg = lane >> 3;            // edge slot 0..7
    int cq = lane & 7;             // channel quad: channels cq*4..cq*4+3
    int hsel = cq >> 2;            // head for this lane's channels
    int beg = binptr[n], end = binptr[n + 1];
    float2 ad = a_dst2[n];
    const unsigned char* xpb = xp1f8 + cq * 4;

    float acc0 = 0.f, acc1 = 0.f, acc2 = 0.f, acc3 = 0.f, ssum = 0.f;
    for (int i0 = beg; i0 < end; i0 += 64) {
        int cw = end - i0;
        if (cw > 64) cw = 64;
        int s_l = 0;
        unsigned int pk_l = 0u;
        if (lane < cw) {
            s_l = srt[i0 + lane];
            float2 as = a_src2[s_l];
            float e0 = __expf(leaky(as.x + ad.x));
            float e1 = __expf(leaky(as.y + ad.y));
            // pack as 2x bf16 (round-half-up)
            pk_l = ((__float_as_uint(e1) + 0x8000u) & 0xFFFF0000u) |
                   ((__float_as_uint(e0) + 0x8000u) >> 16);
        }
        // tiered consume: wave-uniform branch, each tier fully unrolled
        if (cw > 48)      { AGG1_CONSUME(8) }
        else if (cw > 32) { AGG1_CONSUME(6) }
        else if (cw > 16) { AGG1_CONSUME(4) }
        else              { AGG1_CONSUME(2) }
    }
    // reduce across the 8 edge slots (lane bits 3..5)
#pragma unroll
    for (int off = 8; off <= 32; off <<= 1) {
        acc0 += __shfl_xor(acc0, off);
        acc1 += __shfl_xor(acc1, off);
        acc2 += __shfl_xor(acc2, off);
        acc3 += __shfl_xor(acc3, off);
        ssum += __shfl_xor(ssum, off);
    }
    float inv = 1.f / (ssum + EPS);
    int j0 = cq * 4;
    float p;
    {
        float hv0 = fmaxf(acc0 * inv + b1[j0 + 0], 0.f);
        float hv1 = fmaxf(acc1 * inv + b1[j0 + 1], 0.f);
        float hv2 = fmaxf(acc2 * inv + b1[j0 + 2], 0.f);
        float hv3 = fmaxf(acc3 * inv + b1[j0 + 3], 0.f);
        p = hv0 * W2[j0 + 0];
        p = fmaf(hv1, W2[j0 + 1], p);
        p = fmaf(hv2, W2[j0 + 2], p);
        p = fmaf(hv3, W2[j0 + 3], p);
    }
    // reduce across the 8 channel quads (lane bits 0..2)
    p += __shfl_xor(p, 1);
    p += __shfl_xor(p, 2);
    p += __shfl_xor(p, 4);
    if (lane == 0) xp2[n] = p;
}

// ---- fused layer-2 aggregation: 2 nodes per 32-lane slot (2x gather MLP) ----
__global__ __launch_bounds__(256) void agg2_kernel(
    const int* __restrict__ binptr, const int* __restrict__ srt,
    const float* __restrict__ xp2, const float* __restrict__ as2p,
    const float* __restrict__ ad2p, const float* __restrict__ b2,
    float* __restrict__ partial, int N) {
    int slot = (blockIdx.x * blockDim.x + threadIdx.x) >> 5;
    int j = threadIdx.x & 31;
    int nslots = (gridDim.x * blockDim.x) >> 5;
    float as2 = as2p[0], ad2 = ad2p[0], bb = b2[0];
    float val = 0.f;
    for (int n0 = slot; n0 < N; n0 += 2 * nslots) {
        int n1 = n0 + nslots;
        bool has1 = n1 < N;
        int beg0 = binptr[n0], end0 = binptr[n0 + 1];
        int beg1 = has1 ? binptr[n1] : 0;
        int end1 = has1 ? binptr[n1 + 1] : 0;
        float xd0 = xp2[n0] * ad2;
        float xd1 = has1 ? xp2[n1] * ad2 : 0.f;
        float se0 = 0.f, sa0 = 0.f, se1 = 0.f, sa1 = 0.f;
        int it0 = (end0 - beg0 - j + 31) >> 5;   // iterations for lane j
        int it1 = (end1 - beg1 - j + 31) >> 5;
        int itm = it0 > it1 ? it0 : it1;
        for (int k = 0; k < itm; k++) {
            int i0 = beg0 + j + k * 32;
            int i1 = beg1 + j + k * 32;
            if (i0 < end0) {
                float xs = xp2[srt[i0]];
                float ex = __expf(leaky(fmaf(xs, as2, xd0)));
                se0 += ex; sa0 = fmaf(ex, xs, sa0);
            }
            if (has1 && i1 < end1) {
                float xs = xp2[srt[i1]];
                float ex = __expf(leaky(fmaf(xs, as2, xd1)));
                se1 += ex; sa1 = fmaf(ex, xs, sa1);
            }
        }
#pragma unroll
        for (int off = 16; off >= 1; off >>= 1) {
            se0 += __shfl_xor(se0, off);
            sa0 += __shfl_xor(sa0, off);
            se1 += __shfl_xor(se1, off);
            sa1 += __shfl_xor(sa1, off);
        }
        if (j == 0) {
            val += sa0 / (se0 + EPS) + bb;
            if (has1) val += sa1 / (se1 + EPS) + bb;
        }
    }
#pragma unroll
    for (int off = 32; off >= 1; off >>= 1) val += __shfl_xor(val, off);
    __shared__ float ls[4];
    int lane = threadIdx.x & 63, w = threadIdx.x >> 6;
    if (lane == 0) ls[w] = val;
    __syncthreads();
    if (threadIdx.x == 0) partial[blockIdx.x] = ls[0] + ls[1] + ls[2] + ls[3];
}

// ---------------- final: out[0] = sum of partials ----------------
__global__ void final_reduce(const float* __restrict__ partial, float* __restrict__ out,
                             int P) {
    int t = threadIdx.x;
    float v = 0.f;
    for (int i = t; i < P; i += 1024) v += partial[i];
#pragma unroll
    for (int off = 32; off >= 1; off >>= 1) v += __shfl_xor(v, off);
    __shared__ float ls[16];
    int w = t >> 6, lane = t & 63;
    if (lane == 0) ls[w] = v;
    __syncthreads();
    if (t == 0) {
        float s = 0.f;
        for (int i = 0; i < 16; i++) s += ls[i];
        out[0] = s;
    }
}

extern "C" void kernel_launch(void* const* d_in, const int* in_sizes, int n_in,
                              void* d_out, int out_size, void* d_ws, size_t ws_size,
                              hipStream_t stream) {
    const float* x        = (const float*)d_in[0];
    const int*   ei       = (const int*)d_in[1];
    const float* W1       = (const float*)d_in[2];
    const float* att_src1 = (const float*)d_in[3];
    const float* att_dst1 = (const float*)d_in[4];
    const float* b1       = (const float*)d_in[5];
    const float* W2       = (const float*)d_in[6];
    const float* att_src2 = (const float*)d_in[7];
    const float* att_dst2 = (const float*)d_in[8];
    const float* b2       = (const float*)d_in[9];
    float* out = (float*)d_out;

    int N = in_sizes[0] / 128;
    int E = in_sizes[1] / 2;
    int ET = E + N;
    int NB = (N + BNODES - 1) / BNODES;        // 391 buckets
    int NC = (ET + CHUNK - 1) / CHUNK;         // 806 chunks
    int n_scan = NB * NC;                      // ~315K
    int nb2 = (n_scan + 1023) / 1024;          // ~308 scan blocks (<=1024)
    const int AGG2_BLOCKS = 2048;

    char* w = (char*)d_ws;
    unsigned char* xp1f8 = (unsigned char*)w; w += (size_t)N * 32;
    float* a_src   = (float*)w;  w += sizeof(float) * (size_t)N * 2;
    float* a_dst   = (float*)w;  w += sizeof(float) * (size_t)N * 2;
    float* xp2     = (float*)w;  w += sizeof(float) * (size_t)N;
    int* cnt       = (int*)w;    w += sizeof(int) * (size_t)n_scan;
    int* scanned   = (int*)w;    w += sizeof(int) * (size_t)(n_scan + 4);
    int* partials  = (int*)w;    w += sizeof(int) * 1024;
    float* part2   = (float*)w;  w += sizeof(float) * (size_t)AGG2_BLOCKS;
    unsigned int* packed = (unsigned int*)w; w += sizeof(unsigned int) * (size_t)ET;
    int* srt       = (int*)w;    w += sizeof(int) * (size_t)ET;
    int* binptr    = (int*)w;    w += sizeof(int) * (size_t)(N + 1);

    gemm1_kernel<<<(N + 63) / 64, 256, 0, stream>>>(x, W1,
                                                    (const float4*)att_src1,
                                                    (const float4*)att_dst1,
                                                    (unsigned int*)xp1f8, a_src,
                                                    a_dst, N);
    chunkhist_kernel<<<NC, 1024, 0, stream>>>(ei, E, ET, NB, NC, cnt);
    scan_block<<<nb2, 1024, 0, stream>>>(cnt, scanned, partials, n_scan);
    scan_partials<<<1, 1024, 0, stream>>>(partials, nb2);
    packsort_kernel<<<NC, 1024, 0, stream>>>(ei, E, ET, NB, NC, scanned, partials,
                                             packed);
    localsort_kernel<<<NB, 1024, 0, stream>>>(packed, scanned, partials, NB, NC, ET,
                                              srt, binptr, N);
    agg1_kernel<<<(N * 64 + 255) / 256, 256, 0, stream>>>(binptr, srt,
                                                          (const float2*)a_src,
                                                          (const float2*)a_dst,
                                                          xp1f8, b1, W2, xp2, N);
    agg2_kernel<<<AGG2_BLOCKS, 256, 0, stream>>>(binptr, srt, xp2,
                                                 att_src2, att_dst2, b2, part2, N);
    final_reduce<<<1, 1024, 0, stream>>>(part2, out, AGG2_BLOCKS);
}